// Round 4
// baseline (371.892 us; speedup 1.0000x reference)
//
#include <hip/hip_runtime.h>

#define Hdim 128
#define Tlen 512
#define BT 8      // batch rows per block -> grid 256 = 1 block/CU
#define STR 136   // padded LDS row stride in fp16 elems (272B = 17x16B)

typedef __attribute__((ext_vector_type(8))) _Float16 f16x8;
typedef __attribute__((ext_vector_type(2))) _Float16 f16x2;
typedef __attribute__((ext_vector_type(4))) float f32x4;

__device__ __forceinline__ f32x4 mfma_f16(f16x8 a, f16x8 b, f32x4 c) {
  return __builtin_amdgcn_mfma_f32_16x16x32_f16(a, b, c, 0, 0, 0);
}

// R14 = R13 bit-exact + latency-chain restructure (model-discriminating).
// Counter calibration (R10->R13 delta): -12 trans/SIMD -> -99 cyc/step =>
// trans ~ 8-10 cyc/wave64 (quarter-rate). Ambiguity: VALUBusy*step = 832
// exceeds counted pure-VALU (~250/wave) unless VALUBusy INCLUDES MFMA issue;
// if so, true idle ~760 cyc/step = latency stall (ds_read ~120 + MFMA RAW
// hazards + trans-ladder serial chain), not issue-bound. R14 attacks latency
// BIT-EXACTLY (absmax must stay exactly 0.0078125 — doubles as a check):
//  1. dpp -> own-lane cndmask: lane n+8's acc regs 2,3 are bitwise equal to
//     lane n's (duplicate B-cols), so the cross-lane dpp is replaceable by a
//     same-lane reg select; removes the long MFMA->DPP RAW-hazard nops.
//  2. chain-o deferred: issue i,f,g chains first, start their select/G/exp2
//     under o's 4-MFMA issue+latency; cn's rcp->exp2 ladder overlaps o.
//     Pure cross-chain reorder: each chain's internal q-order unchanged.
//  3. float4 x prefetch, clamp logic hoisted out of the main loop.
// If latency-bound: 315-335 us, MfmaUtil ~37-39%. If issue-port-bound:
// ~340-347 us -> next round goes pure instruction-count (paired rcp).
// Structure: 8 waves, BT=8, wave w owns gate rows 16w..16w+15 per gate type;
// B cols 8-15 duplicate 0-7; h fp16 RNE; c fp32-resident; 1 barrier/step;
// W pre-scaled -log2e (i,f,o) / +2log2e (g); pointwise 5 exp2 + 2 rcp/cell.
__global__ __launch_bounds__(512, 2)
void lstm_disc_kernel(const float* __restrict__ x, const float* __restrict__ hx0,
                      const float* __restrict__ cx0, const float* __restrict__ W_ih,
                      const float* __restrict__ W_hh, const float* __restrict__ b_ih,
                      const float* __restrict__ b_hh, const float* __restrict__ W_mlp,
                      const float* __restrict__ b_mlp, float* __restrict__ out) {
  __shared__ _Float16 hbuf0[BT * STR];
  __shared__ _Float16 hbuf1[BT * STR];

  const int tid  = threadIdx.x;
  const int w    = tid >> 6;          // wave 0..7
  const int lane = tid & 63;
  const int l16  = lane & 15;         // B col n / A row m
  const int quad = lane >> 4;         // 0..3
  const int b0   = blockIdx.x * BT;
  const int bb   = l16 & 7;           // batch row (cols 8-15 duplicate 0-7)
  const bool hi  = (l16 < 8);
  const int uoff = quad * 4 + (hi ? 0 : 2);   // in-wave unit offset (even)
  const int ub   = 16 * w + uoff;             // first owned unit

  // ---- A fragments: W_hh pre-scaled; x/bias terms in final cell layout ----
  f16x8 wh[4][4];
  float wihG[4][2], biasG[4][2];
#pragma unroll
  for (int s = 0; s < 4; s++) {
    const float sc = (s == 2) ? 2.88539008f : -1.44269504f;  // g : i,f,o
    const int j = 16 * w + 128 * s + l16;       // gate row, type s
#pragma unroll
    for (int q = 0; q < 4; q++) {
      const float* p = W_hh + j * Hdim + q * 32 + quad * 8;
      f16x8 f;
#pragma unroll
      for (int e = 0; e < 8; e++) f[e] = (_Float16)(p[e] * sc);
      wh[s][q] = f;
    }
#pragma unroll
    for (int r2 = 0; r2 < 2; r2++) {
      const int j2 = 16 * w + 128 * s + uoff + r2;
      wihG[s][r2]  = W_ih[j2] * sc;
      biasG[s][r2] = (b_ih[j2] + b_hh[j2]) * sc;
    }
  }

  // ---- h0 -> LDS rows 0-7, fp16 RNE ----
  for (int i = tid; i < BT * Hdim; i += 512) {
    const int b = i >> 7, k = i & 127;
    hbuf0[b * STR + k] = (_Float16)hx0[(b0 + b) * Hdim + k];
  }

  // ---- c0: lane owns units ub, ub+1 of batch bb ----
  float c[2] = {cx0[(b0 + bb) * Hdim + ub], cx0[(b0 + bb) * Hdim + ub + 1]};

  const float* xp = x + (b0 + bb) * Tlen;   // row base, 2048B-aligned
  float4 xq = *(const float4*)&xp[0];

  __syncthreads();

  const f32x4 Z = {0.0f, 0.0f, 0.0f, 0.0f};

  auto step = [&](const _Float16* __restrict__ src, _Float16* __restrict__ dst,
                  float xcur) {
    // B frags: B[k=quad*8+e][n=l16], col n = batch bb (8-15 broadcast-dup)
    f16x8 bfrag[4];
#pragma unroll
    for (int q = 0; q < 4; q++)
      bfrag[q] = *(const f16x8*)&src[bb * STR + q * 32 + quad * 8];

    // chains i,f,g issued first (q-interleaved; per-chain order unchanged)
    f32x4 ai = mfma_f16(wh[0][0], bfrag[0], Z);
    f32x4 af = mfma_f16(wh[1][0], bfrag[0], Z);
    f32x4 ag = mfma_f16(wh[2][0], bfrag[0], Z);
#pragma unroll
    for (int q = 1; q < 4; q++) {
      ai = mfma_f16(wh[0][q], bfrag[q], ai);
      af = mfma_f16(wh[1][q], bfrag[q], af);
      ag = mfma_f16(wh[2][q], bfrag[q], ag);
    }

    // select (own-lane; bitwise = old dpp route) + G + exp2 for i,f,g
    float A[2], F[2], Bv[2];
#pragma unroll
    for (int r2 = 0; r2 < 2; r2++) {
      float gi = hi ? ai[r2] : ai[2 + r2];
      float gf = hi ? af[r2] : af[2 + r2];
      float gg = hi ? ag[r2] : ag[2 + r2];
      float Gi = __builtin_fmaf(xcur, wihG[0][r2], gi + biasG[0][r2]);
      float Gf = __builtin_fmaf(xcur, wihG[1][r2], gf + biasG[1][r2]);
      float Gg = __builtin_fmaf(xcur, wihG[2][r2], gg + biasG[2][r2]);
      A[r2]  = __builtin_amdgcn_exp2f(Gi);   // e^{-i}
      F[r2]  = __builtin_amdgcn_exp2f(Gf);   // e^{-f}
      Bv[r2] = __builtin_amdgcn_exp2f(Gg);   // e^{2g}
    }

    // chain o issued here: its pipe latency overlaps the cn ladder below
    f32x4 ao = mfma_f16(wh[3][0], bfrag[0], Z);
#pragma unroll
    for (int q = 1; q < 4; q++) ao = mfma_f16(wh[3][q], bfrag[q], ao);

    // cn ladder (needs A,F,Bv only) — expressions verbatim from R13
    float cnv[2], D[2];
#pragma unroll
    for (int r2 = 0; r2 < 2; r2++) {
      float a1 = 1.0f + A[r2], b1 = 1.0f + Bv[r2], f1 = 1.0f + F[r2];
      float t1 = a1 * b1;
      float num = __builtin_fmaf(c[r2], t1, (Bv[r2] - 1.0f) * f1);
      float cn  = num * __builtin_amdgcn_rcpf(t1 * f1);
      c[r2] = cn;
      cnv[r2] = cn;
      D[r2] = __builtin_amdgcn_exp2f(cn * 2.88539008f);  // e^{2*cn}
    }

    // o select + G + exp2, then hv
    float hv[2];
#pragma unroll
    for (int r2 = 0; r2 < 2; r2++) {
      float go = hi ? ao[r2] : ao[2 + r2];
      float Go = __builtin_fmaf(xcur, wihG[3][r2], go + biasG[3][r2]);
      float O  = __builtin_amdgcn_exp2f(Go);             // e^{-o}
      hv[r2] = (D[r2] - 1.0f) *
               __builtin_amdgcn_rcpf((1.0f + O) * (1.0f + D[r2]));
    }
    f16x2 hp;
    hp[0] = (_Float16)hv[0];   // RNE
    hp[1] = (_Float16)hv[1];
    *(f16x2*)&dst[bb * STR + ub] = hp;

    __syncthreads();
  };

  // main loop: float4 prefetch (t+4..t+7 valid through t=504)
  for (int t = 0; t < Tlen - 4; t += 4) {
    float4 xn = *(const float4*)&xp[t + 4];
    step(hbuf0, hbuf1, xq.x);
    step(hbuf1, hbuf0, xq.y);
    step(hbuf0, hbuf1, xq.z);
    step(hbuf1, hbuf0, xq.w);
    xq = xn;
  }
  // final group t=508: no prefetch
  step(hbuf0, hbuf1, xq.x);
  step(hbuf1, hbuf0, xq.y);
  step(hbuf0, hbuf1, xq.z);
  step(hbuf1, hbuf0, xq.w);

  // ---- epilogue: out[b] = sigmoid(h . W_mlp + b_mlp); final h in hbuf0 ----
  if (tid < BT) {
    float s = 0.0f;
#pragma unroll 8
    for (int k = 0; k < Hdim; k++)
      s += (float)hbuf0[tid * STR + k] * W_mlp[k];
    out[b0 + tid] = __builtin_amdgcn_rcpf(
        1.0f + __builtin_amdgcn_exp2f((s + b_mlp[0]) * -1.44269504f));
  }
}

extern "C" void kernel_launch(void* const* d_in, const int* in_sizes, int n_in,
                              void* d_out, int out_size, void* d_ws, size_t ws_size,
                              hipStream_t stream) {
  const float* x     = (const float*)d_in[0];
  const float* hx0   = (const float*)d_in[1];
  const float* cx0   = (const float*)d_in[2];
  const float* W_ih  = (const float*)d_in[3];
  const float* W_hh  = (const float*)d_in[4];
  const float* b_ih  = (const float*)d_in[5];
  const float* b_hh  = (const float*)d_in[6];
  const float* W_mlp = (const float*)d_in[7];
  const float* b_mlp = (const float*)d_in[8];
  float* out = (float*)d_out;

  const int B = in_sizes[1] / Hdim;   // hx0 is [B, H]
  dim3 grid(B / BT), block(512);
  lstm_disc_kernel<<<grid, block, 0, stream>>>(x, hx0, cx0, W_ih, W_hh, b_ih,
                                               b_hh, W_mlp, b_mlp, out);
}

// Round 5
// 348.249 us; speedup vs baseline: 1.0679x; 1.0679x over previous
//
#include <hip/hip_runtime.h>

#define Hdim 128
#define Tlen 512
#define BT 8      // batch rows per block -> grid 256 = 1 block/CU
#define STR 136   // padded LDS row stride in fp16 elems (272B = 17x16B)

typedef __attribute__((ext_vector_type(8))) _Float16 f16x8;
typedef __attribute__((ext_vector_type(2))) _Float16 f16x2;
typedef __attribute__((ext_vector_type(4))) float f32x4;

__device__ __forceinline__ f32x4 mfma_f16(f16x8 a, f16x8 b, f32x4 c) {
  return __builtin_amdgcn_mfma_f32_16x16x32_f16(a, b, c, 0, 0, 0);
}
// dest lane i (within 16-lane DPP row): i>=8 gets src lane i-8's v; i<8 keeps
// `old` (bound_ctrl=false). Rebalances C-regs 2,3 onto the duplicate lanes.
__device__ __forceinline__ float dpp_shl8(float old, float v) {
  int r = __builtin_amdgcn_update_dpp(__builtin_bit_cast(int, old),
                                      __builtin_bit_cast(int, v),
                                      0x108 /*row_shl:8*/, 0xF, 0xF, false);
  return __builtin_bit_cast(float, r);
}

// R15 = R13 byte-identical EXCEPT the in-loop barrier: __syncthreads ->
// {s_waitcnt lgkmcnt(0); s_barrier} (no vmcnt drain). Single-variable A/B.
// R14 post-mortem: chain-split regressed (+25 us, o-chain tail latency
// exposed) and broke bit-exactness -> fully reverted.
// Theory: __syncthreads emits s_waitcnt vmcnt(0) lgkmcnt(0) before s_barrier
// (compiler must conservatively drain globals). Our x-prefetch loads are
// cold HBM misses (~900 cyc, x read exactly once) issued at each 4-step
// group top; the next step-end barrier drains vmcnt(0) -> exposes cold-miss
// latency every 4 steps (~100-200 cyc/step amortized) + 512 pointless full
// drains. LDS recurrence correctness only needs lgkmcnt(0) before s_barrier:
// a wave's src-buffer ds_reads are complete before it reaches the barrier
// (its own MFMAs consumed them via compiler lgkmcnt waits), and the
// double-buffer handles write/read hazards across steps.
// Predict: absmax EXACTLY 0.0078125 (bit-exact check); 300-330 us if the
// drain theory holds; neutral => structural floor, consider ROOFLINE.
// Structure: 8 waves, BT=8, wave w owns gate rows 16w..16w+15 per gate type;
// B cols 8-15 duplicate 0-7; h fp16 RNE; c fp32-resident; 1 barrier/step;
// W pre-scaled -log2e (i,f,o) / +2log2e (g); pointwise 5 exp2 + 2 rcp/cell.
__global__ __launch_bounds__(512, 2)
void lstm_disc_kernel(const float* __restrict__ x, const float* __restrict__ hx0,
                      const float* __restrict__ cx0, const float* __restrict__ W_ih,
                      const float* __restrict__ W_hh, const float* __restrict__ b_ih,
                      const float* __restrict__ b_hh, const float* __restrict__ W_mlp,
                      const float* __restrict__ b_mlp, float* __restrict__ out) {
  __shared__ _Float16 hbuf0[BT * STR];
  __shared__ _Float16 hbuf1[BT * STR];

  const int tid  = threadIdx.x;
  const int w    = tid >> 6;          // wave 0..7
  const int lane = tid & 63;
  const int l16  = lane & 15;         // B col n / A row m
  const int quad = lane >> 4;         // 0..3
  const int b0   = blockIdx.x * BT;
  const int bb   = l16 & 7;           // batch row (cols 8-15 duplicate 0-7)
  const bool hi  = (l16 < 8);
  const int uoff = quad * 4 + (hi ? 0 : 2);   // in-wave unit offset (even)
  const int ub   = 16 * w + uoff;             // first owned unit

  // ---- A fragments: W_hh pre-scaled; x/bias terms in final cell layout ----
  f16x8 wh[4][4];
  float wihG[4][2], biasG[4][2];
#pragma unroll
  for (int s = 0; s < 4; s++) {
    const float sc = (s == 2) ? 2.88539008f : -1.44269504f;  // g : i,f,o
    const int j = 16 * w + 128 * s + l16;       // gate row, type s
#pragma unroll
    for (int q = 0; q < 4; q++) {
      const float* p = W_hh + j * Hdim + q * 32 + quad * 8;
      f16x8 f;
#pragma unroll
      for (int e = 0; e < 8; e++) f[e] = (_Float16)(p[e] * sc);
      wh[s][q] = f;
    }
#pragma unroll
    for (int r2 = 0; r2 < 2; r2++) {
      const int j2 = 16 * w + 128 * s + uoff + r2;
      wihG[s][r2]  = W_ih[j2] * sc;
      biasG[s][r2] = (b_ih[j2] + b_hh[j2]) * sc;
    }
  }

  // ---- h0 -> LDS rows 0-7, fp16 RNE ----
  for (int i = tid; i < BT * Hdim; i += 512) {
    const int b = i >> 7, k = i & 127;
    hbuf0[b * STR + k] = (_Float16)hx0[(b0 + b) * Hdim + k];
  }

  // ---- c0: lane owns units ub, ub+1 of batch bb ----
  float c[2] = {cx0[(b0 + bb) * Hdim + ub], cx0[(b0 + bb) * Hdim + ub + 1]};

  const float* xp = x + (b0 + bb) * Tlen;
  float xv[4] = {xp[0], xp[1], xp[2], xp[3]};

  __syncthreads();

  const f32x4 Z = {0.0f, 0.0f, 0.0f, 0.0f};

  auto step = [&](const _Float16* __restrict__ src, _Float16* __restrict__ dst,
                  float xcur) {
    // B frags: B[k=quad*8+e][n=l16], col n = batch bb (8-15 broadcast-dup)
    f16x8 bfrag[4];
#pragma unroll
    for (int q = 0; q < 4; q++)
      bfrag[q] = *(const f16x8*)&src[bb * STR + q * 32 + quad * 8];

    // four independent 4-deep MFMA chains (gate types i,f,g,o)
    f32x4 a[4];
#pragma unroll
    for (int s = 0; s < 4; s++) a[s] = mfma_f16(wh[s][0], bfrag[0], Z);
#pragma unroll
    for (int q = 1; q < 4; q++)
#pragma unroll
      for (int s = 0; s < 4; s++) a[s] = mfma_f16(wh[s][q], bfrag[q], a[s]);

    // rebalance: lanes >=8 take regs 2,3 from lane-8; add bias + x*W_ih
    float G[4][2];
#pragma unroll
    for (int s = 0; s < 4; s++)
#pragma unroll
      for (int r2 = 0; r2 < 2; r2++) {
        float g = dpp_shl8(a[s][r2], a[s][2 + r2]);
        G[s][r2] = __builtin_fmaf(xcur, wihG[s][r2], g + biasG[s][r2]);
      }

    // LSTM pointwise, 2 cells/lane, common-denominator forms: 5 exp2 + 2 rcp
    float hv[2];
#pragma unroll
    for (int r2 = 0; r2 < 2; r2++) {
      float A  = __builtin_amdgcn_exp2f(G[0][r2]);   // e^{-i}
      float F  = __builtin_amdgcn_exp2f(G[1][r2]);   // e^{-f}
      float Bv = __builtin_amdgcn_exp2f(G[2][r2]);   // e^{2g}
      float O  = __builtin_amdgcn_exp2f(G[3][r2]);   // e^{-o}
      float a1 = 1.0f + A, b1 = 1.0f + Bv, f1 = 1.0f + F;
      float t1 = a1 * b1;
      float num = __builtin_fmaf(c[r2], t1, (Bv - 1.0f) * f1);
      float cn  = num * __builtin_amdgcn_rcpf(t1 * f1);
      c[r2] = cn;
      float D  = __builtin_amdgcn_exp2f(cn * 2.88539008f);  // e^{2*cn}
      hv[r2] = (D - 1.0f) *
               __builtin_amdgcn_rcpf((1.0f + O) * (1.0f + D));
    }
    f16x2 hp;
    hp[0] = (_Float16)hv[0];   // RNE
    hp[1] = (_Float16)hv[1];
    *(f16x2*)&dst[bb * STR + ub] = hp;

    // raw barrier: wait LDS ops only — do NOT drain vmcnt (x prefetch
    // loads stay in flight across steps; they're consumed from VGPRs).
    asm volatile("s_waitcnt lgkmcnt(0)" ::: "memory");
    __builtin_amdgcn_s_barrier();
  };

  for (int t = 0; t < Tlen; t += 4) {
    const int tn = t + 4;
    float xa = xp[(tn     < Tlen) ? tn     : Tlen - 1];
    float xb = xp[(tn + 1 < Tlen) ? tn + 1 : Tlen - 1];
    float xc = xp[(tn + 2 < Tlen) ? tn + 2 : Tlen - 1];
    float xd = xp[(tn + 3 < Tlen) ? tn + 3 : Tlen - 1];
    step(hbuf0, hbuf1, xv[0]);
    step(hbuf1, hbuf0, xv[1]);
    step(hbuf0, hbuf1, xv[2]);
    step(hbuf1, hbuf0, xv[3]);
    xv[0] = xa; xv[1] = xb; xv[2] = xc; xv[3] = xd;
  }

  // ---- epilogue: out[b] = sigmoid(h . W_mlp + b_mlp); final h in hbuf0 ----
  // last step's {lgkmcnt(0); s_barrier} makes all h writes visible.
  if (tid < BT) {
    float s = 0.0f;
#pragma unroll 8
    for (int k = 0; k < Hdim; k++)
      s += (float)hbuf0[tid * STR + k] * W_mlp[k];
    out[b0 + tid] = __builtin_amdgcn_rcpf(
        1.0f + __builtin_amdgcn_exp2f((s + b_mlp[0]) * -1.44269504f));
  }
}

extern "C" void kernel_launch(void* const* d_in, const int* in_sizes, int n_in,
                              void* d_out, int out_size, void* d_ws, size_t ws_size,
                              hipStream_t stream) {
  const float* x     = (const float*)d_in[0];
  const float* hx0   = (const float*)d_in[1];
  const float* cx0   = (const float*)d_in[2];
  const float* W_ih  = (const float*)d_in[3];
  const float* W_hh  = (const float*)d_in[4];
  const float* b_ih  = (const float*)d_in[5];
  const float* b_hh  = (const float*)d_in[6];
  const float* W_mlp = (const float*)d_in[7];
  const float* b_mlp = (const float*)d_in[8];
  float* out = (float*)d_out;

  const int B = in_sizes[1] / Hdim;   // hx0 is [B, H]
  dim3 grid(B / BT), block(512);
  lstm_disc_kernel<<<grid, block, 0, stream>>>(x, hx0, cx0, W_ih, W_hh, b_ih,
                                               b_hh, W_mlp, b_mlp, out);
}